// Round 3
// baseline (659.961 us; speedup 1.0000x reference)
//
#include <hip/hip_runtime.h>

#define DEVI __device__ __forceinline__

typedef __attribute__((ext_vector_type(8))) short s16x8;
typedef __attribute__((ext_vector_type(4))) float f32x4;

// np.linspace(1, 168, 32).astype(int64)
__device__ __constant__ int LAGS_C[32] = {
    1,6,11,17,22,27,33,38,44,49,54,60,65,71,76,81,
    87,92,97,103,108,114,119,124,130,135,141,146,151,157,162,168};

DEVI unsigned short f2bf(float f) {
  unsigned u = __float_as_uint(f);
  return (unsigned short)((u + 0x7FFFu + ((u >> 16) & 1u)) >> 16);
}
DEVI unsigned pk2(float a, float b) {
  return (unsigned)f2bf(a) | ((unsigned)f2bf(b) << 16);
}
DEVI float bf2f(unsigned short u) {
  return __uint_as_float(((unsigned)u) << 16);
}

DEVI f32x4 mfma16(s16x8 a, s16x8 b, f32x4 c) {
  asm("v_mfma_f32_16x16x32_bf16 %0, %1, %2, %0" : "+v"(c) : "v"(a), "v"(b));
  return c;
}

DEVI void gl_lds16(const void* g, void* l) {
  __builtin_amdgcn_global_load_lds(
      (const __attribute__((address_space(1))) unsigned int*)g,
      (__attribute__((address_space(3))) unsigned int*)l, 16, 0, 0);
}

// ---------------- xm = mean over D ----------------
__global__ __launch_bounds__(256) void k_mean(const float* __restrict__ x,
                                              float* __restrict__ xm) {
  int row = blockIdx.x * 4 + (threadIdx.x >> 6);
  int lane = threadIdx.x & 63;
  const float4* p = (const float4*)(x + (size_t)row * 512 + lane * 8);
  float4 a = p[0], bq = p[1];
  float s = a.x + a.y + a.z + a.w + bq.x + bq.y + bq.z + bq.w;
#pragma unroll
  for (int off = 32; off; off >>= 1) s += __shfl_xor(s, off, 64);
  if (lane == 0) xm[row] = s * (1.0f / 512.0f);
}

// ---------------- proj_w fp32 -> bf16 ----------------
__global__ __launch_bounds__(256) void k_cvt(const float* __restrict__ pw,
                                             unsigned short* __restrict__ pwb) {
  int i = (blockIdx.x * 256 + threadIdx.x) * 4;
  float4 v = *(const float4*)(pw + i);
  ushort4 o;
  o.x = f2bf(v.x); o.y = f2bf(v.y); o.z = f2bf(v.z); o.w = f2bf(v.w);
  *(ushort4*)(pwb + i) = o;
}

// ---------------- lag scores ----------------
__global__ __launch_bounds__(256) void k_scores(const float* __restrict__ xm,
                                                float* __restrict__ scores) {
  __shared__ float xs[2048];
  int b = blockIdx.x, tid = threadIdx.x;
  const float4* src = (const float4*)(xm + b * 2048);
  float4* dst = (float4*)xs;
  for (int i = tid; i < 512; i += 256) dst[i] = src[i];
  __syncthreads();
  int wid = tid >> 6, lane = tid & 63;
  for (int j = 0; j < 8; ++j) {
    int li = wid * 8 + j;
    int lag = LAGS_C[li];
    int n = 2048 - lag;
    float p = 0.f;
    for (int t = lane; t < n; t += 64) p += xs[t] * xs[t + lag];
#pragma unroll
    for (int off = 32; off; off >>= 1) p += __shfl_xor(p, off, 64);
    if (lane == 0) scores[b * 32 + li] = p / (float)n;
  }
}

// ---------------- top-5 + normalized weights (register-resident) ----------------
__global__ __launch_bounds__(64) void k_topk(const float* __restrict__ scores,
                                             int* __restrict__ lsel,
                                             float* __restrict__ wsel) {
  int b = threadIdx.x;
  if (b >= 32) return;
  float v[32];
#pragma unroll
  for (int i = 0; i < 32; ++i) v[i] = scores[b * 32 + i];
  unsigned used = 0;
  int idxs[5];
  float vals[5];
#pragma unroll
  for (int j = 0; j < 5; ++j) {
    float best = -3.402823466e38f;
    int bi = 0;
#pragma unroll
    for (int i = 0; i < 32; ++i) {
      if (!((used >> i) & 1u) && v[i] > best) { best = v[i]; bi = i; }
    }
    used |= 1u << bi;
    idxs[j] = bi;
    vals[j] = best;
  }
  float denom = vals[0] + vals[1] + vals[2] + vals[3] + vals[4] + 1e-6f;
#pragma unroll
  for (int j = 0; j < 5; ++j) {
    lsel[b * 5 + j] = LAGS_C[idxs[j]];
    wsel[b * 5 + j] = vals[j] / denom;
  }
}

// ---------------- conv half of A (+ x -> bf16 cast) ----------------
// block 256 thr; tile 16 rows x 256 ch; grid 8192
__global__ __launch_bounds__(256) void k_conv(
    const float* __restrict__ x, const float* __restrict__ cw0,
    const float* __restrict__ cw1, const float* __restrict__ cw2,
    unsigned short* __restrict__ Ab, unsigned short* __restrict__ xbf,
    int useBf) {
  __shared__ float xs[40][256];
  const int tid = threadIdx.x;
  const int rt = blockIdx.x >> 1, cht = blockIdx.x & 1;
  const int L0 = rt << 4;
  const int b = L0 >> 11, l0 = L0 & 2047;
  const int d0 = cht << 8;
  const float* xb = x + (size_t)b * (2048 * 512);

  // stage 40 rows x 256 ch (rows l0-12 .. l0+27), zero-padded at batch edges
#pragma unroll
  for (int p = 0; p < 10; ++p) {
    int idx = tid + p * 256;
    int row = idx >> 6, c = idx & 63;
    int lb = l0 - 12 + row;
    float4 v = make_float4(0.f, 0.f, 0.f, 0.f);
    if (lb >= 0 && lb < 2048) v = *(const float4*)(xb + (size_t)lb * 512 + d0 + c * 4);
    *(float4*)(&xs[row][c * 4]) = v;
  }

  // hoist per-thread weights (4 channels) into registers
  const int chg = tid & 63;
  const int dc = d0 + chg * 4;  // first of 4 channels
  float r0[12], r1[20], r2[28];
#pragma unroll
  for (int i = 0; i < 3; ++i) *(float4*)(&r0[i * 4]) = *(const float4*)(cw0 + dc * 3 + i * 4);
#pragma unroll
  for (int i = 0; i < 5; ++i) *(float4*)(&r1[i * 4]) = *(const float4*)(cw1 + dc * 5 + i * 4);
#pragma unroll
  for (int i = 0; i < 7; ++i) *(float4*)(&r2[i * 4]) = *(const float4*)(cw2 + dc * 7 + i * 4);
  float w[15][4];
#pragma unroll
  for (int c = 0; c < 4; ++c) {
#pragma unroll
    for (int t = 0; t < 3; ++t) w[t][c] = r0[c * 3 + t];
#pragma unroll
    for (int t = 0; t < 5; ++t) w[3 + t][c] = r1[c * 5 + t];
#pragma unroll
    for (int t = 0; t < 7; ++t) w[8 + t][c] = r2[c * 7 + t];
  }
  __syncthreads();

  const int rowg = tid >> 6;
  const int rbase = rowg << 2;
  constexpr int COFF[15] = {-1, 0, 1, -4, -2, 0, 2, 4, -12, -8, -4, 0, 4, 8, 12};
  float acc[4][4];
#pragma unroll
  for (int r = 0; r < 4; ++r)
#pragma unroll
    for (int c = 0; c < 4; ++c) acc[r][c] = 0.f;
  float4 xc[4];
#pragma unroll
  for (int rr = 0; rr < 28; ++rr) {
    float4 xv = *(const float4*)(&xs[rbase + rr][chg * 4]);
    if (rr >= 12 && rr < 16) xc[rr - 12] = xv;
#pragma unroll
    for (int tap = 0; tap < 15; ++tap) {
      const int tr = rr - 12 - COFF[tap];
      if (tr >= 0 && tr < 4) {
        acc[tr][0] = fmaf(w[tap][0], xv.x, acc[tr][0]);
        acc[tr][1] = fmaf(w[tap][1], xv.y, acc[tr][1]);
        acc[tr][2] = fmaf(w[tap][2], xv.z, acc[tr][2]);
        acc[tr][3] = fmaf(w[tap][3], xv.w, acc[tr][3]);
      }
    }
  }
#pragma unroll
  for (int r = 0; r < 4; ++r) {
    size_t grow = (size_t)L0 + rbase + r;
    uint2 oc;
    oc.x = pk2(acc[r][0], acc[r][1]);
    oc.y = pk2(acc[r][2], acc[r][3]);
    *(uint2*)(Ab + grow * 1024 + dc) = oc;
    if (useBf) {
      uint2 ox;
      ox.x = pk2(xc[r].x, xc[r].y);
      ox.y = pk2(xc[r].z, xc[r].w);
      *(uint2*)(xbf + grow * 512 + dc) = ox;
    }
  }
}

// ---------------- autocorr half of A (5-lag weighted gather) ----------------
// block 256 thr; tile 16 rows x 512 ch; grid 4096
__global__ __launch_bounds__(256) void k_auto(
    const float* __restrict__ x, const unsigned short* __restrict__ xbf,
    const int* __restrict__ lsel, const float* __restrict__ wsel,
    unsigned short* __restrict__ Ab, int useBf) {
  const int tid = threadIdx.x;
  const int chg = tid & 63, rowg = tid >> 6;
  const int L0 = blockIdx.x << 4;
  const int b = L0 >> 11, lb0 = L0 & 2047;
  int lag[5];
  float wv[5];
#pragma unroll
  for (int j = 0; j < 5; ++j) {
    lag[j] = lsel[b * 5 + j];
    wv[j] = wsel[b * 5 + j];
  }
#pragma unroll
  for (int r = 0; r < 4; ++r) {
    int l = lb0 + rowg * 4 + r;
    float s[8];
#pragma unroll
    for (int c = 0; c < 8; ++c) s[c] = 0.f;
#pragma unroll
    for (int j = 0; j < 5; ++j) {
      int sl = (l - lag[j]) & 2047;
      float wj = wv[j];
      if (useBf) {
        s16x8 v = *(const s16x8*)(xbf + ((size_t)b * 2048 + sl) * 512 + chg * 8);
#pragma unroll
        for (int c = 0; c < 8; ++c)
          s[c] = fmaf(wj, bf2f((unsigned short)v[c]), s[c]);
      } else {
        const float* p = x + ((size_t)b * 2048 + sl) * 512 + chg * 8;
        float4 lo = *(const float4*)p;
        float4 hi = *(const float4*)(p + 4);
        s[0] = fmaf(wj, lo.x, s[0]); s[1] = fmaf(wj, lo.y, s[1]);
        s[2] = fmaf(wj, lo.z, s[2]); s[3] = fmaf(wj, lo.w, s[3]);
        s[4] = fmaf(wj, hi.x, s[4]); s[5] = fmaf(wj, hi.y, s[5]);
        s[6] = fmaf(wj, hi.z, s[6]); s[7] = fmaf(wj, hi.w, s[7]);
      }
    }
    uint4 o;
    o.x = pk2(s[0], s[1]); o.y = pk2(s[2], s[3]);
    o.z = pk2(s[4], s[5]); o.w = pk2(s[6], s[7]);
    *(uint4*)(Ab + (size_t)(L0 + rowg * 4 + r) * 1024 + 512 + chg * 8) = o;
  }
}

// ---------------- GEMM + bias + residual + LN ----------------
// BM=32, BN=512, BK=32; 256 thr (4 waves, 1x4); A in LDS (dbuf, 4KB),
// B fragments direct from global (L1/L2-resident pwb). grid 2048.
__global__ __launch_bounds__(256) void k_gemm(
    const unsigned short* __restrict__ Ab, const unsigned short* __restrict__ pwb,
    const float* __restrict__ x, const float* __restrict__ pb,
    const float* __restrict__ lng, const float* __restrict__ lnb,
    float* __restrict__ out) {
  __shared__ __align__(16) char smem[4096];  // A dbuf; epilogue overlays
  float2* red = (float2*)smem;               // [32][4]
  float2* rstat = (float2*)(smem + 1024);    // [32]

  const int tid = threadIdx.x;
  const int lane = tid & 63;
  const int wid = tid >> 6;  // == wc (0..3)
  const int lr = lane & 15, g4 = lane >> 4;
  const int m0 = blockIdx.x << 5;

  // A staging (threads 0..127 stage 32 rows x 32 cols = 2 KB per buffer)
  const int sr = (tid & 127) >> 2;
  const int ssl = (tid & 3) ^ ((sr >> 1) & 3);
  const unsigned short* aSrc = Ab + (size_t)(m0 + sr) * 1024 + ssl * 8;

  // A fragment read offset (swizzled)
  const int aoff = lr * 64 + ((g4 ^ ((lr >> 1) & 3)) << 4);
  // B fragment base: row = wid*128 + n*16 + lr, col g4*8 (+ kt*32)
  const unsigned short* bBase = pwb + (size_t)(wid * 128 + lr) * 1024 + g4 * 8;

  f32x4 acc[2][8];
#pragma unroll
  for (int m = 0; m < 2; ++m)
#pragma unroll
    for (int n = 0; n < 8; ++n) acc[m][n] = f32x4{0.f, 0.f, 0.f, 0.f};

#define STAGE(b_, kt)                                                   \
  do {                                                                  \
    if (wid < 2) gl_lds16(aSrc + (kt) * 32, smem + (b_) * 2048 + wid * 1024); \
  } while (0)

  STAGE(0, 0);
  __syncthreads();
#pragma unroll 1
  for (int kt = 0; kt < 32; ++kt) {
    const int cur = kt & 1;
    if (kt < 31) STAGE(cur ^ 1, kt + 1);
    const char* ab = smem + cur * 2048;
    s16x8 af0 = *(const s16x8*)(ab + aoff);
    s16x8 af1 = *(const s16x8*)(ab + aoff + 1024);
    s16x8 bf[8];
#pragma unroll
    for (int n = 0; n < 8; ++n)
      bf[n] = *(const s16x8*)(bBase + (size_t)n * 16384 + kt * 32);
#pragma unroll
    for (int n = 0; n < 8; ++n) {
      acc[0][n] = mfma16(af0, bf[n], acc[0][n]);
      acc[1][n] = mfma16(af1, bf[n], acc[1][n]);
    }
    __syncthreads();
  }
#undef STAGE

  // epilogue: h = x + (y + bias); LayerNorm over D=512; store
  float pbv[8], gv[8], bv[8];
#pragma unroll
  for (int n = 0; n < 8; ++n) {
    int c = wid * 128 + n * 16 + lr;
    pbv[n] = pb[c];
    gv[n] = lng[c];
    bv[n] = lnb[c];
  }
#pragma unroll
  for (int m = 0; m < 2; ++m) {
#pragma unroll
    for (int reg = 0; reg < 4; ++reg) {
      int row = m * 16 + g4 * 4 + reg;
      const float* xp = x + (size_t)(m0 + row) * 512 + wid * 128 + lr;
      float s1 = 0.f, s2 = 0.f;
#pragma unroll
      for (int n = 0; n < 8; ++n) {
        float h = acc[m][n][reg] + pbv[n] + xp[n * 16];
        acc[m][n][reg] = h;
        s1 += h;
        s2 += h * h;
      }
#pragma unroll
      for (int off = 1; off < 16; off <<= 1) {
        s1 += __shfl_xor(s1, off, 64);
        s2 += __shfl_xor(s2, off, 64);
      }
      if (lr == 0) red[row * 4 + wid] = make_float2(s1, s2);
    }
  }
  __syncthreads();
  if (tid < 32) {
    float s1 = 0.f, s2 = 0.f;
#pragma unroll
    for (int w4 = 0; w4 < 4; ++w4) {
      float2 p = red[tid * 4 + w4];
      s1 += p.x;
      s2 += p.y;
    }
    float mu = s1 * (1.f / 512.f);
    float var = s2 * (1.f / 512.f) - mu * mu;
    rstat[tid] = make_float2(mu, rsqrtf(var + 1e-5f));
  }
  __syncthreads();
#pragma unroll
  for (int m = 0; m < 2; ++m) {
#pragma unroll
    for (int reg = 0; reg < 4; ++reg) {
      int row = m * 16 + g4 * 4 + reg;
      float2 st = rstat[row];
      float* op = out + (size_t)(m0 + row) * 512 + wid * 128 + lr;
#pragma unroll
      for (int n = 0; n < 8; ++n)
        op[n * 16] = (acc[m][n][reg] - st.x) * st.y * gv[n] + bv[n];
    }
  }
}

extern "C" void kernel_launch(void* const* d_in, const int* in_sizes, int n_in,
                              void* d_out, int out_size, void* d_ws, size_t ws_size,
                              hipStream_t stream) {
  const float* x = (const float*)d_in[0];
  const float* cw0 = (const float*)d_in[1];
  const float* cw1 = (const float*)d_in[2];
  const float* cw2 = (const float*)d_in[3];
  const float* pw = (const float*)d_in[4];
  const float* pb = (const float*)d_in[5];
  const float* lng = (const float*)d_in[6];
  const float* lnb = (const float*)d_in[7];
  float* out = (float*)d_out;

  char* ws = (char*)d_ws;
  float* xm = (float*)ws;                                // 65536 f32 (256 KB)
  float* scores = (float*)(ws + 262144);                 // 32x32 f32
  int* lsel = (int*)(ws + 266240);                       // 32x5 int
  float* wsel = (float*)(ws + 266880);                   // 32x5 f32
  unsigned short* pwb = (unsigned short*)(ws + 267520);  // 512x1024 bf16 (1 MB)
  unsigned short* Ab = (unsigned short*)(ws + 1316096);  // [65536][1024] bf16 (134 MB)
  unsigned short* xbf = (unsigned short*)(ws + 135533824);  // [65536][512] bf16 (67 MB)

  int useBf = (ws_size >= 202642688ull) ? 1 : 0;

  k_mean<<<16384, 256, 0, stream>>>(x, xm);
  k_cvt<<<512, 256, 0, stream>>>(pw, pwb);
  k_conv<<<8192, 256, 0, stream>>>(x, cw0, cw1, cw2, Ab, xbf, useBf);
  k_scores<<<32, 256, 0, stream>>>(xm, scores);
  k_topk<<<1, 64, 0, stream>>>(scores, lsel, wsel);
  k_auto<<<4096, 256, 0, stream>>>(x, xbf, lsel, wsel, Ab, useBf);
  k_gemm<<<2048, 256, 0, stream>>>(Ab, pwb, x, pb, lng, lnb, out);
}

// Round 4
// 506.567 us; speedup vs baseline: 1.3028x; 1.3028x over previous
//
#include <hip/hip_runtime.h>

#define DEVI __device__ __forceinline__

typedef __attribute__((ext_vector_type(8))) short s16x8;
typedef __attribute__((ext_vector_type(4))) float f32x4;

// np.linspace(1, 168, 32).astype(int64)
__device__ __constant__ int LAGS_C[32] = {
    1,6,11,17,22,27,33,38,44,49,54,60,65,71,76,81,
    87,92,97,103,108,114,119,124,130,135,141,146,151,157,162,168};

DEVI unsigned short f2bf(float f) {
  unsigned u = __float_as_uint(f);
  return (unsigned short)((u + 0x7FFFu + ((u >> 16) & 1u)) >> 16);
}
DEVI unsigned pk2(float a, float b) {
  return (unsigned)f2bf(a) | ((unsigned)f2bf(b) << 16);
}
DEVI float bf2f(unsigned short u) {
  return __uint_as_float(((unsigned)u) << 16);
}

DEVI f32x4 mfma16(s16x8 a, s16x8 b, f32x4 c) {
  asm("v_mfma_f32_16x16x32_bf16 %0, %1, %2, %0" : "+v"(c) : "v"(a), "v"(b));
  return c;
}

DEVI void gl_lds16(const void* g, void* l) {
  __builtin_amdgcn_global_load_lds(
      (const __attribute__((address_space(1))) unsigned int*)g,
      (__attribute__((address_space(3))) unsigned int*)l, 16, 0, 0);
}

// ---------------- fused: x -> (xm row-means, conv half of A, xbf) ----------------
// block 256 thr; tile 16 L-rows x 512 ch; grid 4096
__global__ __launch_bounds__(256) void k_pre(
    const float* __restrict__ x, const float* __restrict__ cw0,
    const float* __restrict__ cw1, const float* __restrict__ cw2,
    unsigned short* __restrict__ Ab, unsigned short* __restrict__ xbf,
    float* __restrict__ xm, int useBf) {
  __shared__ float xs[40][512];  // 80 KB
  const int tid = threadIdx.x;
  const int L0 = blockIdx.x << 4;
  const int b = L0 >> 11, l0 = L0 & 2047;
  const float* xb = x + (size_t)b * (2048 * 512);

  // stage rows l0-12 .. l0+27 (zero-padded at batch edges); emit xbf inline
#pragma unroll
  for (int p = 0; p < 20; ++p) {
    int i = tid + p * 256;
    int row = i >> 7, c4 = i & 127;
    int lb = l0 - 12 + row;
    float4 v = make_float4(0.f, 0.f, 0.f, 0.f);
    if (lb >= 0 && lb < 2048) v = *(const float4*)(xb + (size_t)lb * 512 + c4 * 4);
    *(float4*)(&xs[row][c4 * 4]) = v;
    if (useBf && row >= 12 && row < 28) {
      uint2 o;
      o.x = pk2(v.x, v.y);
      o.y = pk2(v.z, v.w);
      *(uint2*)(xbf + (size_t)(L0 + row - 12) * 512 + c4 * 4) = o;
    }
  }

  // per-thread conv weights: 4 channels x 15 taps
  const int chg = tid & 127;
  const int dc = chg * 4;
  float w[15][4];
  {
    float r0[12], r1[20], r2[28];
#pragma unroll
    for (int i = 0; i < 3; ++i) *(float4*)(&r0[i * 4]) = *(const float4*)(cw0 + dc * 3 + i * 4);
#pragma unroll
    for (int i = 0; i < 5; ++i) *(float4*)(&r1[i * 4]) = *(const float4*)(cw1 + dc * 5 + i * 4);
#pragma unroll
    for (int i = 0; i < 7; ++i) *(float4*)(&r2[i * 4]) = *(const float4*)(cw2 + dc * 7 + i * 4);
#pragma unroll
    for (int c = 0; c < 4; ++c) {
#pragma unroll
      for (int t = 0; t < 3; ++t) w[t][c] = r0[c * 3 + t];
#pragma unroll
      for (int t = 0; t < 5; ++t) w[3 + t][c] = r1[c * 5 + t];
#pragma unroll
      for (int t = 0; t < 7; ++t) w[8 + t][c] = r2[c * 7 + t];
    }
  }
  __syncthreads();

  // row means: 16 rows x 16 thr/row, 32 ch each; rotated start to spread banks
  {
    int row = tid >> 4, seg = tid & 15;
    float s = 0.f;
#pragma unroll
    for (int q = 0; q < 8; ++q) {
      int qq = (q + seg) & 7;
      float4 v = *(const float4*)(&xs[row + 12][seg * 32 + qq * 4]);
      s += v.x + v.y + v.z + v.w;
    }
#pragma unroll
    for (int off = 1; off < 16; off <<= 1) s += __shfl_xor(s, off, 64);
    if (seg == 0) xm[L0 + row] = s * (1.f / 512.f);
  }

  // conv: each thread 8 rows x 4 ch, sliding read of 32 staged rows
  const int rbase = (tid >> 7) << 3;
  constexpr int COFF[15] = {-1, 0, 1, -4, -2, 0, 2, 4, -12, -8, -4, 0, 4, 8, 12};
  float acc[8][4];
#pragma unroll
  for (int r = 0; r < 8; ++r)
#pragma unroll
    for (int c = 0; c < 4; ++c) acc[r][c] = 0.f;
#pragma unroll
  for (int rr = 0; rr < 32; ++rr) {
    float4 xv = *(const float4*)(&xs[rbase + rr][dc]);
#pragma unroll
    for (int tap = 0; tap < 15; ++tap) {
      const int tr = rr - 12 - COFF[tap];
      if (tr >= 0 && tr < 8) {
        acc[tr][0] = fmaf(w[tap][0], xv.x, acc[tr][0]);
        acc[tr][1] = fmaf(w[tap][1], xv.y, acc[tr][1]);
        acc[tr][2] = fmaf(w[tap][2], xv.z, acc[tr][2]);
        acc[tr][3] = fmaf(w[tap][3], xv.w, acc[tr][3]);
      }
    }
  }
#pragma unroll
  for (int r = 0; r < 8; ++r) {
    size_t grow = (size_t)L0 + rbase + r;
    uint2 oc;
    oc.x = pk2(acc[r][0], acc[r][1]);
    oc.y = pk2(acc[r][2], acc[r][3]);
    *(uint2*)(Ab + grow * 1024 + dc) = oc;
  }
}

// ---------------- proj_w fp32 -> bf16 ----------------
__global__ __launch_bounds__(256) void k_cvt(const float* __restrict__ pw,
                                             unsigned short* __restrict__ pwb) {
  int i = (blockIdx.x * 256 + threadIdx.x) * 4;
  float4 v = *(const float4*)(pw + i);
  ushort4 o;
  o.x = f2bf(v.x); o.y = f2bf(v.y); o.z = f2bf(v.z); o.w = f2bf(v.w);
  *(ushort4*)(pwb + i) = o;
}

// ---------------- lag scores ----------------
__global__ __launch_bounds__(256) void k_scores(const float* __restrict__ xm,
                                                float* __restrict__ scores) {
  __shared__ float xs[2048];
  int b = blockIdx.x, tid = threadIdx.x;
  const float4* src = (const float4*)(xm + b * 2048);
  float4* dst = (float4*)xs;
  for (int i = tid; i < 512; i += 256) dst[i] = src[i];
  __syncthreads();
  int wid = tid >> 6, lane = tid & 63;
  for (int j = 0; j < 8; ++j) {
    int li = wid * 8 + j;
    int lag = LAGS_C[li];
    int n = 2048 - lag;
    float p = 0.f;
    for (int t = lane; t < n; t += 64) p += xs[t] * xs[t + lag];
#pragma unroll
    for (int off = 32; off; off >>= 1) p += __shfl_xor(p, off, 64);
    if (lane == 0) scores[b * 32 + li] = p / (float)n;
  }
}

// ---------------- top-5 + normalized weights ----------------
__global__ __launch_bounds__(64) void k_topk(const float* __restrict__ scores,
                                             int* __restrict__ lsel,
                                             float* __restrict__ wsel) {
  int b = threadIdx.x;
  if (b >= 32) return;
  float v[32];
#pragma unroll
  for (int i = 0; i < 32; ++i) v[i] = scores[b * 32 + i];
  unsigned used = 0;
  int idxs[5];
  float vals[5];
#pragma unroll
  for (int j = 0; j < 5; ++j) {
    float best = -3.402823466e38f;
    int bi = 0;
#pragma unroll
    for (int i = 0; i < 32; ++i) {
      if (!((used >> i) & 1u) && v[i] > best) { best = v[i]; bi = i; }
    }
    used |= 1u << bi;
    idxs[j] = bi;
    vals[j] = best;
  }
  float denom = vals[0] + vals[1] + vals[2] + vals[3] + vals[4] + 1e-6f;
#pragma unroll
  for (int j = 0; j < 5; ++j) {
    lsel[b * 5 + j] = LAGS_C[idxs[j]];
    wsel[b * 5 + j] = vals[j] / denom;
  }
}

// ---------------- autocorr half of A (5-lag weighted gather) ----------------
// block 256 thr; tile 16 rows x 512 ch; grid 4096
__global__ __launch_bounds__(256) void k_auto(
    const float* __restrict__ x, const unsigned short* __restrict__ xbf,
    const int* __restrict__ lsel, const float* __restrict__ wsel,
    unsigned short* __restrict__ Ab, int useBf) {
  const int tid = threadIdx.x;
  const int chg = tid & 63, rowg = tid >> 6;
  const int L0 = blockIdx.x << 4;
  const int b = L0 >> 11, lb0 = L0 & 2047;
  int lag[5];
  float wv[5];
#pragma unroll
  for (int j = 0; j < 5; ++j) {
    lag[j] = lsel[b * 5 + j];
    wv[j] = wsel[b * 5 + j];
  }
#pragma unroll
  for (int r = 0; r < 4; ++r) {
    int l = lb0 + rowg * 4 + r;
    float s[8];
#pragma unroll
    for (int c = 0; c < 8; ++c) s[c] = 0.f;
#pragma unroll
    for (int j = 0; j < 5; ++j) {
      int sl = (l - lag[j]) & 2047;
      float wj = wv[j];
      if (useBf) {
        s16x8 v = *(const s16x8*)(xbf + ((size_t)b * 2048 + sl) * 512 + chg * 8);
#pragma unroll
        for (int c = 0; c < 8; ++c)
          s[c] = fmaf(wj, bf2f((unsigned short)v[c]), s[c]);
      } else {
        const float* p = x + ((size_t)b * 2048 + sl) * 512 + chg * 8;
        float4 lo = *(const float4*)p;
        float4 hi = *(const float4*)(p + 4);
        s[0] = fmaf(wj, lo.x, s[0]); s[1] = fmaf(wj, lo.y, s[1]);
        s[2] = fmaf(wj, lo.z, s[2]); s[3] = fmaf(wj, lo.w, s[3]);
        s[4] = fmaf(wj, hi.x, s[4]); s[5] = fmaf(wj, hi.y, s[5]);
        s[6] = fmaf(wj, hi.z, s[6]); s[7] = fmaf(wj, hi.w, s[7]);
      }
    }
    uint4 o;
    o.x = pk2(s[0], s[1]); o.y = pk2(s[2], s[3]);
    o.z = pk2(s[4], s[5]); o.w = pk2(s[6], s[7]);
    *(uint4*)(Ab + (size_t)(L0 + rowg * 4 + r) * 1024 + 512 + chg * 8) = o;
  }
}

// ---------------- GEMM + bias + residual + LN ----------------
// BM=128, BN=512, BK=32; 512 thr (8 waves 2x4); 3-deep LDS pipeline with
// counted vmcnt (T3/T4) + raw s_barrier + setprio. grid 512.
__global__ __launch_bounds__(512, 1) void k_gemm(
    const unsigned short* __restrict__ Ab, const unsigned short* __restrict__ pwb,
    const float* __restrict__ x, const unsigned short* __restrict__ xbf,
    const float* __restrict__ pb, const float* __restrict__ lng,
    const float* __restrict__ lnb, float* __restrict__ out, int useBf) {
  __shared__ __align__(16) char smem[122880];  // 3 x (A 8KB + B 32KB)
  float2* red = (float2*)smem;                 // [128][4] overlay (post-loop)
  float2* rstat = (float2*)(smem + 4096);      // [128]

  const int tid = threadIdx.x;
  const int lane = tid & 63;
  const int wid = tid >> 6;
  const int wr = wid >> 2, wc = wid & 3;
  const int lr = lane & 15, g4 = lane >> 4;
  const int m0 = blockIdx.x << 7;

  // staging: lane's source slot XOR-swizzled; LDS dest linear (G21 both-sides)
  const int sr = tid >> 2;
  const int ssl = (tid & 3) ^ ((sr >> 1) & 3);
  const unsigned short* aSrc = Ab + (size_t)(m0 + sr) * 1024 + ssl * 8;
  const unsigned short* bSrc0 = pwb + (size_t)sr * 1024 + ssl * 8;

  f32x4 acc[4][8];
#pragma unroll
  for (int m = 0; m < 4; ++m)
#pragma unroll
    for (int n = 0; n < 8; ++n) acc[m][n] = f32x4{0.f, 0.f, 0.f, 0.f};

  const int swsl = (g4 ^ ((lr >> 1) & 3)) << 4;
  const int aoff = (wr * 64 + lr) * 64 + swsl;
  const int boff = (wc * 128 + lr) * 64 + swsl;

#define STAGE(base_, kt)                                                      \
  do {                                                                        \
    char* db_ = smem + (base_);                                               \
    gl_lds16(aSrc + (kt) * 32, db_ + wid * 1024);                             \
    _Pragma("unroll") for (int i_ = 0; i_ < 4; ++i_)                          \
        gl_lds16(bSrc0 + (size_t)i_ * 131072 + (kt) * 32,                     \
                 db_ + 8192 + i_ * 8192 + wid * 1024);                        \
  } while (0)

  STAGE(0, 0);
  STAGE(40960, 1);
  STAGE(81920, 2);
  int cur = 0;
#pragma unroll 1
  for (int kt = 0; kt < 32; ++kt) {
    // counted wait: keep the two newer stages (10 loads/thread) in flight
    if (kt < 30) asm volatile("s_waitcnt vmcnt(10)" ::: "memory");
    else if (kt == 30) asm volatile("s_waitcnt vmcnt(5)" ::: "memory");
    else asm volatile("s_waitcnt vmcnt(0)" ::: "memory");
    __builtin_amdgcn_s_barrier();
    __builtin_amdgcn_sched_barrier(0);
    const char* ab = smem + cur * 40960;
    const char* bb = ab + 8192;
    s16x8 af[4];
#pragma unroll
    for (int m = 0; m < 4; ++m) af[m] = *(const s16x8*)(ab + aoff + m * 1024);
    __builtin_amdgcn_s_setprio(1);
#pragma unroll
    for (int n = 0; n < 8; ++n) {
      s16x8 bf = *(const s16x8*)(bb + boff + n * 1024);
#pragma unroll
      for (int m = 0; m < 4; ++m) acc[m][n] = mfma16(af[m], bf, acc[m][n]);
    }
    __builtin_amdgcn_s_setprio(0);
    __builtin_amdgcn_sched_barrier(0);
    __builtin_amdgcn_s_barrier();
    __builtin_amdgcn_sched_barrier(0);
    if (kt < 29) STAGE(cur * 40960, kt + 3);
    cur = (cur == 2) ? 0 : cur + 1;
  }
  __syncthreads();

  // epilogue: h = x + (y + bias); LayerNorm over D=512; store
  float pbv[8], gv[8], bv[8];
#pragma unroll
  for (int n = 0; n < 8; ++n) {
    int c = wc * 128 + n * 16 + lr;
    pbv[n] = pb[c];
    gv[n] = lng[c];
    bv[n] = lnb[c];
  }
#pragma unroll
  for (int m = 0; m < 4; ++m) {
#pragma unroll
    for (int reg = 0; reg < 4; ++reg) {
      int row = wr * 64 + m * 16 + g4 * 4 + reg;
      float xr[8];
      if (useBf) {
        const unsigned short* xp = xbf + (size_t)(m0 + row) * 512 + wc * 128 + lr;
#pragma unroll
        for (int n = 0; n < 8; ++n) xr[n] = bf2f(xp[n * 16]);
      } else {
        const float* xp = x + (size_t)(m0 + row) * 512 + wc * 128 + lr;
#pragma unroll
        for (int n = 0; n < 8; ++n) xr[n] = xp[n * 16];
      }
      float s1 = 0.f, s2 = 0.f;
#pragma unroll
      for (int n = 0; n < 8; ++n) {
        float h = acc[m][n][reg] + pbv[n] + xr[n];
        acc[m][n][reg] = h;
        s1 += h;
        s2 += h * h;
      }
#pragma unroll
      for (int off = 1; off < 16; off <<= 1) {
        s1 += __shfl_xor(s1, off, 64);
        s2 += __shfl_xor(s2, off, 64);
      }
      if (lr == 0) red[row * 4 + wc] = make_float2(s1, s2);
    }
  }
  __syncthreads();
  if (tid < 128) {
    float s1 = 0.f, s2 = 0.f;
#pragma unroll
    for (int w4 = 0; w4 < 4; ++w4) {
      float2 p = red[tid * 4 + w4];
      s1 += p.x;
      s2 += p.y;
    }
    float mu = s1 * (1.f / 512.f);
    float var = s2 * (1.f / 512.f) - mu * mu;
    rstat[tid] = make_float2(mu, rsqrtf(var + 1e-5f));
  }
  __syncthreads();
#pragma unroll
  for (int m = 0; m < 4; ++m) {
#pragma unroll
    for (int reg = 0; reg < 4; ++reg) {
      int row = wr * 64 + m * 16 + g4 * 4 + reg;
      float2 st = rstat[row];
      float* op = out + (size_t)(m0 + row) * 512 + wc * 128 + lr;
#pragma unroll
      for (int n = 0; n < 8; ++n)
        op[n * 16] = (acc[m][n][reg] - st.x) * st.y * gv[n] + bv[n];
    }
  }
}

extern "C" void kernel_launch(void* const* d_in, const int* in_sizes, int n_in,
                              void* d_out, int out_size, void* d_ws, size_t ws_size,
                              hipStream_t stream) {
  const float* x = (const float*)d_in[0];
  const float* cw0 = (const float*)d_in[1];
  const float* cw1 = (const float*)d_in[2];
  const float* cw2 = (const float*)d_in[3];
  const float* pw = (const float*)d_in[4];
  const float* pb = (const float*)d_in[5];
  const float* lng = (const float*)d_in[6];
  const float* lnb = (const float*)d_in[7];
  float* out = (float*)d_out;

  char* ws = (char*)d_ws;
  float* xm = (float*)ws;                                // 65536 f32 (256 KB)
  float* scores = (float*)(ws + 262144);                 // 32x32 f32
  int* lsel = (int*)(ws + 266240);                       // 32x5 int
  float* wsel = (float*)(ws + 266880);                   // 32x5 f32
  unsigned short* pwb = (unsigned short*)(ws + 267520);  // 512x1024 bf16 (1 MB)
  unsigned short* Ab = (unsigned short*)(ws + 1316096);  // [65536][1024] bf16 (134 MB)
  unsigned short* xbf = (unsigned short*)(ws + 135533824);  // [65536][512] bf16 (67 MB)

  int useBf = (ws_size >= 202642688ull) ? 1 : 0;

  k_pre<<<4096, 256, 0, stream>>>(x, cw0, cw1, cw2, Ab, xbf, xm, useBf);
  k_cvt<<<512, 256, 0, stream>>>(pw, pwb);
  k_scores<<<32, 256, 0, stream>>>(xm, scores);
  k_topk<<<1, 64, 0, stream>>>(scores, lsel, wsel);
  k_auto<<<4096, 256, 0, stream>>>(x, xbf, lsel, wsel, Ab, useBf);
  k_gemm<<<512, 512, 0, stream>>>(Ab, pwb, x, xbf, pb, lng, lnb, out, useBf);
}